// Round 4
// baseline (101.442 us; speedup 1.0000x reference)
//
#include <hip/hip_runtime.h>
#include <stdint.h>
#include <stddef.h>

typedef __bf16 bf16_t;
typedef __bf16 bf16x8 __attribute__((ext_vector_type(8)));
typedef float  f32x4  __attribute__((ext_vector_type(4)));

#define NIMG 16
#define CIN  128
#define COUT 128
#define HH   56
#define WW   56
#define HW   (HH * WW)       // 3136
#define CDIM 58              // staged c extent: c = w+1, w = -1..56
#define LSTR 136             // LDS c-stride in bf16: 272B = 68 dwords -> bank stride 4
#define RECB 272             // bytes per (row,c) record: 256 B data + 16 B pad
#define SLABB (CDIM * RECB)  // 15,776 B per input-row slab (bf16, pre-padded)
#define SLABU (SLABB / 16)   // 986 16-byte units per slab
#define STAGEU (4 * SLABU)   // 3944 units staged per conv block (slabs are contiguous)
#define ROWPAIRS 28
#define WT2_BYTES 294912     // 288 records * 1024 B; bf16 slab tensor follows in ws
#define WTBLKS 72            // wtrans: 288 recs * 64 lanes = 18432 thr = EXACTLY 72 blocks

// ---------- prologue (merged): weight transform + input fp32->bf16 slab build ----------
// blocks 0..71: wtrans — one thread per 16B output run (rec,lane):
//   rec = (khkw*4+chunk)*8 + cotile  (rec < 288! round-0..3 launched 2x the threads;
//   junk recs 288..575 overwrote bytes 294912..589823 = the slab region -> the race
//   that failed rounds 2/3. Grid fixed to 72 + guard.)
// blocks 72..999: input convert — block (n, s): slab s=r+1 in [0,58); builds the
//   exact 15,776 B LDS image conv wants ([c][ci] bf16, 272 B records incl. ZEROED
//   16 B pads, zeros baked in for r=-1/56 and w=-1/56), via LDS transpose so
//   loads AND stores coalesce. Fully deterministic workspace content.
__global__ __launch_bounds__(256)
void prologue_kernel(const float* __restrict__ in, const float* __restrict__ w,
                     unsigned char* __restrict__ ws) {
    const int b = blockIdx.x;
    const int tid = threadIdx.x;
    if (b < WTBLKS) {
        bf16_t* wt2 = (bf16_t*)ws;
        int t = b * 256 + tid;                    // 18432 threads total
        int lane = t & 63, rec = t >> 6;          // rec 0..287
        if (rec < 288) {
            int l15 = lane & 15, l4 = lane >> 4;
            int cotile = rec & 7, chunk = (rec >> 3) & 3, khkw = rec >> 5;  // khkw 0..8
            int co  = cotile * 16 + l15;
            int ci0 = chunk * 32 + l4 * 8;
            const float* src = w + ((size_t)co * CIN + ci0) * 9 + khkw;
            bf16x8 o;
#pragma unroll
            for (int j = 0; j < 8; ++j) o[j] = (bf16_t)src[(size_t)j * 9];
            *(bf16x8*)(wt2 + (size_t)rec * 512 + (size_t)lane * 8) = o;
        }
        return;
    }

    __shared__ __align__(16) unsigned char lsm[SLABB];
    const int cb = b - WTBLKS;                    // 0..927
    const int n = cb / CDIM, s = cb - n * CDIM;   // slab s -> input row r = s-1
    const int r = s - 1;
    // phase 1: 986 units (o=0..16 x c=0..57); o=16 is the record pad -> zeros
#pragma unroll
    for (int it = 0; it < 4; ++it) {
        int u = it * 256 + tid;
        if (u < SLABU) {
            int o = u / CDIM, c = u - o * CDIM;
            int w_ = c - 1;
            uint32_t q[8];
            if (o < 16 && r >= 0 && r < HH && w_ >= 0 && w_ < WW) {
                const float* src = in + (((size_t)n * CIN + o * 8) * HH + r) * WW + w_;
                float v[8];
#pragma unroll
                for (int j = 0; j < 8; ++j) v[j] = src[(size_t)j * HW];  // coalesced runs per plane
#pragma unroll
                for (int j = 0; j < 8; ++j) { bf16_t bb = (bf16_t)v[j]; q[j] = *(const uint16_t*)&bb; }
            } else {
#pragma unroll
                for (int j = 0; j < 8; ++j) q[j] = 0;
            }
            uint4 o4;
            o4.x = q[0] | (q[1] << 16); o4.y = q[2] | (q[3] << 16);
            o4.z = q[4] | (q[5] << 16); o4.w = q[6] | (q[7] << 16);
            *(uint4*)&lsm[c * RECB + o * 16] = o4;
        }
    }
    __syncthreads();
    // phase 2: stream slab to workspace (fully coalesced 16B stores)
    uint4* dst = (uint4*)(ws + WT2_BYTES + (size_t)cb * SLABB);
    const uint4* srcl = (const uint4*)lsm;
#pragma unroll
    for (int it = 0; it < 4; ++it) {
        int u = it * 256 + tid;
        if (u < SLABU) dst[u] = srcl[u];
    }
}

// ---------- fused conv: block = (n, 2 rows) x 128 co; 512 thr = 8 waves ----------
// wave = ks*4 + wc*2 + ws: tile 64sp x 64co (tc=4, ts=4), K split in half by ks
// (chunks {2ks,2ks+1} x 9 khkw = 18 phases). LDS cross-wave reduce at the end.
#define FRAG_OFF(I) ((size_t)((((I) >> 1) * 4 + ((I) & 1)) * 8) * 512)

#define MFMA_COL(Mv, TS, F0v, F1v, F2v, F3v)                                          \
    acc[0][TS] = __builtin_amdgcn_mfma_f32_16x16x32_bf16(F0v, Mv, acc[0][TS], 0,0,0); \
    acc[1][TS] = __builtin_amdgcn_mfma_f32_16x16x32_bf16(F1v, Mv, acc[1][TS], 0,0,0); \
    acc[2][TS] = __builtin_amdgcn_mfma_f32_16x16x32_bf16(F2v, Mv, acc[2][TS], 0,0,0); \
    acc[3][TS] = __builtin_amdgcn_mfma_f32_16x16x32_bf16(F3v, Mv, acc[3][TS], 0,0,0);

// All LDS B addresses = per-lane base + compile-time byte immediate (max 40,864 B,
// fits the 16-bit ds offset). Only ts=3 can clamp (ts<=2 max col = 49 <= 57), so
// ts=3 uses one of 3 precomputed clamped bases (selected at compile time per kw).
#define DO_PHASE(I, F0v, F1v, F2v, F3v) do {                                          \
    const int kh_ = ((I) >> 1) / 3, kw_ = ((I) >> 1) % 3, cs_ = (I) & 1;              \
    const bf16_t* b0_ = pB + (size_t)(kh_ * CDIM + kw_) * LSTR + cs_ * 32;            \
    const bf16_t* pb3_ = (kw_ == 0) ? pB3_0 : ((kw_ == 1) ? pB3_1 : pB3_2);           \
    const bf16_t* b3_ = pb3_ + (size_t)(kh_ * CDIM) * LSTR + cs_ * 32;                \
    bf16x8 m0_ = *(const bf16x8*)(b0_);                                               \
    bf16x8 m1_ = *(const bf16x8*)(b0_ + 16 * LSTR);                                   \
    bf16x8 m2_ = *(const bf16x8*)(b0_ + 32 * LSTR);                                   \
    bf16x8 m3_ = *(const bf16x8*)(b3_);                                               \
    __builtin_amdgcn_s_setprio(1);                                                    \
    MFMA_COL(m0_, 0, F0v, F1v, F2v, F3v)                                              \
    MFMA_COL(m1_, 1, F0v, F1v, F2v, F3v)                                              \
    MFMA_COL(m2_, 2, F0v, F1v, F2v, F3v)                                              \
    MFMA_COL(m3_, 3, F0v, F1v, F2v, F3v)                                              \
    __builtin_amdgcn_s_setprio(0);                                                    \
} while (0)

#define PREFETCH(I, F0v, F1v, F2v, F3v) do {                                          \
    const bf16_t* wp_ = wpbase + FRAG_OFF(I);                                         \
    F0v = *(const bf16x8*)(wp_);                                                      \
    F1v = *(const bf16x8*)(wp_ + 512);                                                \
    F2v = *(const bf16x8*)(wp_ + 1024);                                               \
    F3v = *(const bf16x8*)(wp_ + 1536);                                               \
} while (0)

__global__ __launch_bounds__(512, 4)
void conv_fused_kernel(const unsigned char* __restrict__ slabs, const bf16_t* __restrict__ Wt2,
                       const float* __restrict__ bias, float* __restrict__ out) {
    __shared__ __align__(16) unsigned char smem[65536];   // input stage 63104 B / reduce 65536 B
    bf16_t* inp = (bf16_t*)smem;

    // XCD-aware swizzle: grid 448 = 8 XCDs x 56 blocks -> each XCD gets 2 whole
    // images (halo slab re-reads become L2 hits).
    const int bx0 = blockIdx.x;
    const int bx  = (bx0 & 7) * 56 + (bx0 >> 3);

    const int n  = bx / ROWPAIRS;
    const int h0 = (bx % ROWPAIRS) * 2;          // output rows h0,h0+1; slabs h0..h0+3

    const int tid  = threadIdx.x;
    const int lane = tid & 63;
    const int wave = tid >> 6;                   // 0..7
    const int ws  = wave & 1;                    // output row within pair
    const int wc  = (wave >> 1) & 1;             // co half (64)
    const int ks  = wave >> 2;                   // K half (chunks 2ks, 2ks+1)
    const int l15 = lane & 15;
    const int l4  = lane >> 4;

    // ---- stage input: slabs h0..h0+3 are CONTIGUOUS in ws -> flat 63104 B copy.
    // Reg-staged (load-all-then-store): 8 uint4 in flight per thread, zero VALU math.
    {
        const uint4* g = (const uint4*)(slabs + (size_t)n * CDIM * SLABB + (size_t)h0 * SLABB);
        uint4* l = (uint4*)smem;
        uint4 t0 = g[0 * 512 + tid];
        uint4 t1 = g[1 * 512 + tid];
        uint4 t2 = g[2 * 512 + tid];
        uint4 t3 = g[3 * 512 + tid];
        uint4 t4 = g[4 * 512 + tid];
        uint4 t5 = g[5 * 512 + tid];
        uint4 t6 = g[6 * 512 + tid];
        const bool tl = tid < (STAGEU - 3584);   // 360 tail units
        uint4 t7 = g[tl ? (3584 + tid) : 3584];  // clamped addr, store masked below
        l[0 * 512 + tid] = t0;
        l[1 * 512 + tid] = t1;
        l[2 * 512 + tid] = t2;
        l[3 * 512 + tid] = t3;
        l[4 * 512 + tid] = t4;
        l[5 * 512 + tid] = t5;
        l[6 * 512 + tid] = t6;
        if (tl) l[3584 + tid] = t7;
    }
    __syncthreads();

    f32x4 acc[4][4];                             // [co tile][sp tile]
#pragma unroll
    for (int a = 0; a < 4; ++a)
#pragma unroll
        for (int b2 = 0; b2 < 4; ++b2) acc[a][b2] = (f32x4){0.f, 0.f, 0.f, 0.f};

    // weight fragment base: rec = (khkw*4 + ks*2 + cs)*8 + wc*4 + tc
    const bf16_t* wpbase = Wt2 + (size_t)(ks * 16 + wc * 4) * 512 + (size_t)lane * 8;

    // LDS B bases (ws, ks, lane folded in; all phase offsets are compile-time imms)
    const bf16_t* pB = inp + (size_t)(ws * CDIM + l15) * LSTR + ks * 64 + l4 * 8;
    int c3_0 = 48 + l15;     if (c3_0 > 57) c3_0 = 57;    // ts=3 clamped cols per kw
    int c3_1 = 48 + l15 + 1; if (c3_1 > 57) c3_1 = 57;
    int c3_2 = 48 + l15 + 2; if (c3_2 > 57) c3_2 = 57;
    const bf16_t* pB3_0 = inp + (size_t)(ws * CDIM + c3_0) * LSTR + ks * 64 + l4 * 8;
    const bf16_t* pB3_1 = inp + (size_t)(ws * CDIM + c3_1) * LSTR + ks * 64 + l4 * 8;
    const bf16_t* pB3_2 = inp + (size_t)(ws * CDIM + c3_2) * LSTR + ks * 64 + l4 * 8;

    bf16x8 A0, A1, A2, A3, B0, B1, B2, B3;       // named regs, prefetch distance 2
    PREFETCH(0, A0, A1, A2, A3);
    PREFETCH(1, B0, B1, B2, B3);

#pragma unroll
    for (int ii = 0; ii < 8; ++ii) {
        const int i0 = ii * 2;
        DO_PHASE(i0, A0, A1, A2, A3);
        PREFETCH(i0 + 2, A0, A1, A2, A3);
        DO_PHASE(i0 + 1, B0, B1, B2, B3);
        PREFETCH(i0 + 3, B0, B1, B2, B3);
    }
    DO_PHASE(16, A0, A1, A2, A3);
    DO_PHASE(17, B0, B1, B2, B3);

    // ---- cross-wave K reduction through LDS (pair (ws,wc,ks=1) -> (ws,wc,ks=0))
    __syncthreads();                             // K-loop LDS reads done; safe to overwrite
    float* red = (float*)smem;
    const int q = wc * 2 + ws;                   // 0..3
    if (ks == 1) {
#pragma unroll
        for (int tc = 0; tc < 4; ++tc)
#pragma unroll
            for (int ts = 0; ts < 4; ++ts)
                *(f32x4*)(red + (size_t)q * 4096 + (tc * 4 + ts) * 256 + lane * 4) = acc[tc][ts];
    }
    __syncthreads();
    if (ks == 0) {
        const int h   = h0 + ws;
        const int co0 = wc * 64;
        float* obase = out + ((size_t)n * COUT) * HW + (size_t)h * WW;
#pragma unroll
        for (int tc = 0; tc < 4; ++tc) {
#pragma unroll
            for (int ts = 0; ts < 4; ++ts) {
                f32x4 oth = *(const f32x4*)(red + (size_t)q * 4096 + (tc * 4 + ts) * 256 + lane * 4);
                f32x4 r = acc[tc][ts] + oth;
                int w0 = ts * 16 + l15;
                if (w0 < WW) {
#pragma unroll
                    for (int i = 0; i < 4; ++i) {
                        int co = co0 + tc * 16 + l4 * 4 + i;
                        obase[(size_t)co * HW + w0] = r[i] + bias[co];
                    }
                }
            }
        }
    }
}

extern "C" void kernel_launch(void* const* d_in, const int* in_sizes, int n_in,
                              void* d_out, int out_size, void* d_ws, size_t ws_size,
                              hipStream_t stream) {
    const float* in   = (const float*)d_in[0];
    const float* wgt  = (const float*)d_in[1];
    const float* bias = (const float*)d_in[2];
    float* out = (float*)d_out;

    unsigned char* ws = (unsigned char*)d_ws;    // [0, 294912): Wt2; then 14.64 MB bf16 slabs
    bf16_t* Wt2 = (bf16_t*)ws;
    const unsigned char* slabs = ws + WT2_BYTES;

    prologue_kernel<<<WTBLKS + NIMG * CDIM, 256, 0, stream>>>(in, wgt, ws);
    conv_fused_kernel<<<NIMG * ROWPAIRS, 512, 0, stream>>>(slabs, Wt2, bias, out);
}